// Round 3
// baseline (219.545 us; speedup 1.0000x reference)
//
#include <hip/hip_runtime.h>
#include <math.h>

typedef __attribute__((ext_vector_type(8))) short bf16x8;
typedef __attribute__((ext_vector_type(4))) float f32x4;

#define BATCH 32
#define LL    4096
#define FDIM  128
#define NLEV  12
#define EPSF  1e-5f
#define RSQRTF 0.08838834764831845f

// ws layout (float offsets)
#define OFF_CQ 0          // 4096
#define OFF_CK 4096       // 4096
#define OFF_D  8192       // 2 (dq, dk)
#define OFF_SX 8320       // 32*128  (zeroed)
#define OFF_QS 12416      // 32*128  (zeroed)
#define OFF_KS 16512      // 32*128  (zeroed)
#define OFF_DV 20608      // 32*128  dvec
#define OFF_GP 24704      // 8*32*16384 fp32 G partials
#define OFF_GB 4219008    // G bf16: 32*16384 ushort (262144 float slots)
#define OFF_CT 4481152    // Ct bf16: 32*16384 ushort

typedef union { bf16x8 v; unsigned short u[8]; } frag_t;

__device__ inline unsigned short bfr(float f) {   // fp32 -> bf16 RTNE
    union { float f; unsigned u; } v; v.f = f;
    unsigned r = v.u + 0x7FFF + ((v.u >> 16) & 1);
    return (unsigned short)(r >> 16);
}
__device__ inline float bf2f(unsigned short h) {
    union { unsigned u; float f; } v; v.u = ((unsigned)h) << 16; return v.f;
}

// ---------------------------------------------------------------- coeff
// wave collapses to q[b,f] = sum_l cq[l]*x[b,l,f] + dq  (bit_i(l), LSB first)
__global__ void coeff_kernel(const float* __restrict__ qw, const float* __restrict__ qb,
                             const float* __restrict__ kw, const float* __restrict__ kb,
                             float* __restrict__ ws) {
    int l = blockIdx.x * 256 + threadIdx.x;
    float cq = 1.f, ck = 1.f;
#pragma unroll
    for (int i = 0; i < NLEV; i++) {
        int bit = (l >> i) & 1;
        cq *= qw[2 * i + bit];
        ck *= kw[2 * i + bit];
    }
    ws[OFF_CQ + l] = cq;
    ws[OFF_CK + l] = ck;
    if (l == 0) {
        float dq = 0.f, dk = 0.f;
        for (int i = 0; i < NLEV; i++) {
            dq = (qw[2 * i] + qw[2 * i + 1]) * dq + qb[i];
            dk = (kw[2 * i] + kw[2 * i + 1]) * dk + kb[i];
        }
        ws[OFF_D]     = dq;
        ws[OFF_D + 1] = dk;
    }
}

// ---------------------------------------------------------------- K1: G partials + fp32 sums
// grid (8 chunks, 32 batch), 256 thr. G = X^T X ; both MFMA operands share frag values.
__global__ __launch_bounds__(256) void k1_gram(const float* __restrict__ x,
                                               float* __restrict__ ws) {
    __shared__ __align__(16) unsigned short Xs[64][132];
    __shared__ float sa[128], qa[128], ka[128];
    const int b = blockIdx.y, ch = blockIdx.x;
    const int tid = threadIdx.x;
    const int wv = tid >> 6, l15 = tid & 15, quad = (tid >> 4) & 3;
    const float* Xb = x + ((size_t)b * LL + ch * 512) * FDIM;
    const float* cq = ws + OFF_CQ + ch * 512;
    const float* ck = ws + OFF_CK + ch * 512;
    if (tid < 128) { sa[tid] = 0.f; qa[tid] = 0.f; ka[tid] = 0.f; }

    const int srow = tid >> 5;          // 0..7
    const int f0 = (tid & 31) * 4;
    float sx4[4] = {0,0,0,0}, q4[4] = {0,0,0,0}, k4[4] = {0,0,0,0};

    f32x4 acc[2][8];
#pragma unroll
    for (int r_ = 0; r_ < 2; r_++)
#pragma unroll
        for (int c = 0; c < 8; c++) acc[r_][c] = (f32x4){0.f, 0.f, 0.f, 0.f};

    for (int sc = 0; sc < 8; sc++) {
        __syncthreads();
#pragma unroll
        for (int p = 0; p < 8; p++) {
            int r  = p * 8 + srow;
            int gr = sc * 64 + r;
            float4 v = *(const float4*)&Xb[(size_t)gr * FDIM + f0];
            float c1 = cq[gr], c2 = ck[gr];
            sx4[0] += v.x; sx4[1] += v.y; sx4[2] += v.z; sx4[3] += v.w;
            q4[0] += c1 * v.x; q4[1] += c1 * v.y; q4[2] += c1 * v.z; q4[3] += c1 * v.w;
            k4[0] += c2 * v.x; k4[1] += c2 * v.y; k4[2] += c2 * v.z; k4[3] += c2 * v.w;
            ushort4 h; h.x = bfr(v.x); h.y = bfr(v.y); h.z = bfr(v.z); h.w = bfr(v.w);
            *(ushort4*)&Xs[r][f0] = h;
        }
        __syncthreads();
#pragma unroll
        for (int kk = 0; kk < 2; kk++) {
            const int kbase = kk * 32 + quad * 8;
            frag_t fr[8];
#pragma unroll
            for (int c = 0; c < 8; c++)
#pragma unroll
                for (int j = 0; j < 8; j++)
                    fr[c].u[j] = Xs[kbase + j][c * 16 + l15];
#pragma unroll
            for (int r_ = 0; r_ < 2; r_++)
#pragma unroll
                for (int c = 0; c < 8; c++)
                    acc[r_][c] = __builtin_amdgcn_mfma_f32_16x16x32_bf16(
                        fr[2 * wv + r_].v, fr[c].v, acc[r_][c], 0, 0, 0);
        }
    }
    // write partial G
    float* Gp = ws + OFF_GP + (((size_t)ch * 32 + b) << 14);
#pragma unroll
    for (int r_ = 0; r_ < 2; r_++)
#pragma unroll
        for (int c = 0; c < 8; c++)
#pragma unroll
            for (int reg = 0; reg < 4; reg++)
                Gp[(((2 * wv + r_) * 16 + quad * 4 + reg) << 7) + c * 16 + l15] =
                    acc[r_][c][reg];
    // reduce sums
#pragma unroll
    for (int j = 0; j < 4; j++) {
        atomicAdd(&sa[f0 + j], sx4[j]);
        atomicAdd(&qa[f0 + j], q4[j]);
        atomicAdd(&ka[f0 + j], k4[j]);
    }
    __syncthreads();
    if (tid < 128) {
        atomicAdd(&ws[OFF_SX + b * FDIM + tid], sa[tid]);
        atomicAdd(&ws[OFF_QS + b * FDIM + tid], qa[tid]);
        atomicAdd(&ws[OFF_KS + b * FDIM + tid], ka[tid]);
    }
}

// ---------------------------------------------------------------- Kred: sum 8 partials -> G bf16
// grid 128 (b = blk>>2, slice = blk&3 covering 32 rows)
__global__ void kred(float* __restrict__ ws) {
    const int b = blockIdx.x >> 2, s = blockIdx.x & 3;
    const int tid = threadIdx.x;
    const int base = s << 12;           // s*32*128 floats
    float acc[16];
#pragma unroll
    for (int i = 0; i < 16; i++) acc[i] = 0.f;
    for (int ch = 0; ch < 8; ch++) {
        const float* gp = ws + OFF_GP + (((size_t)ch * 32 + b) << 14) + base;
#pragma unroll
        for (int i = 0; i < 4; i++) {
            float4 v = *(const float4*)&gp[(tid + i * 256) * 4];
            acc[i * 4 + 0] += v.x; acc[i * 4 + 1] += v.y;
            acc[i * 4 + 2] += v.z; acc[i * 4 + 3] += v.w;
        }
    }
    unsigned short* gb = (unsigned short*)(ws + OFF_GB) + ((size_t)b << 14) + base;
#pragma unroll
    for (int i = 0; i < 4; i++) {
        ushort4 h;
        h.x = bfr(acc[i * 4 + 0]); h.y = bfr(acc[i * 4 + 1]);
        h.z = bfr(acc[i * 4 + 2]); h.w = bfr(acc[i * 4 + 3]);
        *(ushort4*)&gb[(tid + i * 256) * 4] = h;
    }
}

// ---------------------------------------------------------------- K3: per-batch 128^3 chain -> Ct (bf16), dvec
// grid 32 (one block per batch), 256 thr. P computed on-the-fly from rank-1 scores.
__global__ __launch_bounds__(256) void k3_chain(float* __restrict__ ws,
                                                const float* __restrict__ ffw,
                                                const float* __restrict__ gamma,
                                                const float* __restrict__ beta) {
    __shared__ __align__(16) unsigned short Rt[128][136];
    __shared__ float qs[128], kvv[128], mv[128], invs[128], sxv[128],
                     a1v[128], a2v[128], w0v[128], vacc[128];
    const int b = blockIdx.x, tid = threadIdx.x;
    const int wv = tid >> 6, l15 = tid & 15, quad = (tid >> 4) & 3;
    const unsigned short* Gb = (const unsigned short*)(ws + OFF_GB) + ((size_t)b << 14);

    if (tid < 128) {
        sxv[tid] = ws[OFF_SX + b * FDIM + tid];
        qs[tid]  = (ws[OFF_QS + b * FDIM + tid] + ws[OFF_D]) * RSQRTF;
        kvv[tid] = ws[OFF_KS + b * FDIM + tid] + ws[OFF_D + 1];
        vacc[tid] = 0.f;
    }
    __syncthreads();
    if (tid < 128) {                       // row max + softmax denom (rank-1 scores)
        float qf = qs[tid];
        float mx = -1e30f;
        for (int g = 0; g < 128; g++) mx = fmaxf(mx, qf * kvv[g]);
        float s = 0.f;
        for (int g = 0; g < 128; g++) s += __expf(qf * kvv[g] - mx);
        mv[tid] = mx; invs[tid] = 1.f / s;
    }
    __syncthreads();
    if (tid < 128) {                       // w0 = sX @ P
        int g = tid; float kg = kvv[g];
        float w0 = sxv[g];
        for (int f = 0; f < 128; f++)
            w0 += sxv[f] * __expf(qs[f] * kg - mv[f]) * invs[f];
        w0v[g] = w0;
    }
    __syncthreads();
    // ---- matmul1: T0t = P^T G ; v1*L diag -> vacc
    {
        f32x4 acc[2][8];
#pragma unroll
        for (int r_ = 0; r_ < 2; r_++)
#pragma unroll
            for (int c = 0; c < 8; c++) acc[r_][c] = (f32x4){0.f, 0.f, 0.f, 0.f};
        float kg_r[2];
        kg_r[0] = kvv[(2 * wv + 0) * 16 + l15];
        kg_r[1] = kvv[(2 * wv + 1) * 16 + l15];
        for (int k0 = 0; k0 < 128; k0 += 32) {
            const int kb = k0 + quad * 8;
            frag_t af[2];
#pragma unroll
            for (int r_ = 0; r_ < 2; r_++) {
                int g = (2 * wv + r_) * 16 + l15;
#pragma unroll
                for (int j = 0; j < 8; j++) {
                    int f = kb + j;
                    float v = __expf(qs[f] * kg_r[r_] - mv[f]) * invs[f]
                              + (f == g ? 1.f : 0.f);
                    af[r_].u[j] = bfr(v);
                }
            }
#pragma unroll
            for (int c = 0; c < 8; c++) {
                bf16x8 bb = *(const bf16x8*)(Gb + ((c * 16 + l15) << 7) + kb);
#pragma unroll
                for (int r_ = 0; r_ < 2; r_++)
                    acc[r_][c] = __builtin_amdgcn_mfma_f32_16x16x32_bf16(
                        af[r_].v, bb, acc[r_][c], 0, 0, 0);
            }
        }
#pragma unroll
        for (int r_ = 0; r_ < 2; r_++)
#pragma unroll
            for (int reg = 0; reg < 4; reg++) {
                int g = (2 * wv + r_) * 16 + quad * 4 + reg;
                float kg = kvv[g];
                float ps = 0.f;
#pragma unroll
                for (int c = 0; c < 8; c++) {
                    int f = c * 16 + l15;
                    float p = __expf(qs[f] * kg - mv[f]) * invs[f]
                              + (f == g ? 1.f : 0.f);
                    ps += acc[r_][c][reg] * bf2f(bfr(p));
                }
                ps += __shfl_xor(ps, 1);  ps += __shfl_xor(ps, 2);
                ps += __shfl_xor(ps, 4);  ps += __shfl_xor(ps, 8);
                if (l15 == 0) vacc[g] = ps;
            }
    }
    __syncthreads();
    if (tid < 128) {
        float m1 = w0v[tid] * (1.f / LL);
        float v1 = vacc[tid] * (1.f / LL) - m1 * m1;
        a1v[tid] = gamma[tid] * rsqrtf(v1 + EPSF);
        vacc[tid] = 0.f;
    }
    __syncthreads();
    // ---- matmul2: Rt = M^T * P'^T  (P' = P diag(a1))  -> LDS Rt (bf16)
    {
        f32x4 acc[2][8];
#pragma unroll
        for (int r_ = 0; r_ < 2; r_++)
#pragma unroll
            for (int c = 0; c < 8; c++) acc[r_][c] = (f32x4){0.f, 0.f, 0.f, 0.f};
        float qsr[8], mvr[8], invr[8];
#pragma unroll
        for (int c = 0; c < 8; c++) {
            int f = c * 16 + l15;
            qsr[c] = qs[f]; mvr[c] = mv[f]; invr[c] = invs[f];
        }
        for (int k0 = 0; k0 < 128; k0 += 32) {
            const int kb = k0 + quad * 8;
            frag_t af[2];
#pragma unroll
            for (int r_ = 0; r_ < 2; r_++) {
                int g = (2 * wv + r_) * 16 + l15;
                const float* mp = &ffw[(size_t)g * FDIM + kb];
                float4 m0 = *(const float4*)mp;
                float4 m1_ = *(const float4*)(mp + 4);
                float mm[8] = {m0.x, m0.y, m0.z, m0.w, m1_.x, m1_.y, m1_.z, m1_.w};
#pragma unroll
                for (int j = 0; j < 8; j++) {
                    float v = mm[j] + ((kb + j) == g ? 1.f : 0.f);
                    af[r_].u[j] = bfr(v);
                }
            }
#pragma unroll
            for (int c = 0; c < 8; c++) {
                frag_t bf_;
                int f = c * 16 + l15;
#pragma unroll
                for (int j = 0; j < 8; j++) {
                    int g2 = kb + j;
                    float v = (__expf(qsr[c] * kvv[g2] - mvr[c]) * invr[c]
                               + (f == g2 ? 1.f : 0.f)) * a1v[g2];
                    bf_.u[j] = bfr(v);
                }
#pragma unroll
                for (int r_ = 0; r_ < 2; r_++)
                    acc[r_][c] = __builtin_amdgcn_mfma_f32_16x16x32_bf16(
                        af[r_].v, bf_.v, acc[r_][c], 0, 0, 0);
            }
        }
#pragma unroll
        for (int r_ = 0; r_ < 2; r_++)
#pragma unroll
            for (int c = 0; c < 8; c++)
#pragma unroll
                for (int reg = 0; reg < 4; reg++)
                    Rt[(2 * wv + r_) * 16 + quad * 4 + reg][c * 16 + l15] =
                        bfr(acc[r_][c][reg]);
    }
    __syncthreads();
    // ---- matmul3: T = G * R ; v2*L diag -> vacc (atomic)
    {
        f32x4 acc[2][8];
#pragma unroll
        for (int r_ = 0; r_ < 2; r_++)
#pragma unroll
            for (int c = 0; c < 8; c++) acc[r_][c] = (f32x4){0.f, 0.f, 0.f, 0.f};
        for (int k0 = 0; k0 < 128; k0 += 32) {
            const int kb = k0 + quad * 8;
            bf16x8 af2[2];
#pragma unroll
            for (int r_ = 0; r_ < 2; r_++)
                af2[r_] = *(const bf16x8*)(Gb + (((2 * wv + r_) * 16 + l15) << 7) + kb);
#pragma unroll
            for (int c = 0; c < 8; c++) {
                bf16x8 bb = *(const bf16x8*)&Rt[c * 16 + l15][kb];
#pragma unroll
                for (int r_ = 0; r_ < 2; r_++)
                    acc[r_][c] = __builtin_amdgcn_mfma_f32_16x16x32_bf16(
                        af2[r_], bb, acc[r_][c], 0, 0, 0);
            }
        }
#pragma unroll
        for (int c = 0; c < 8; c++) {
            int g = c * 16 + l15;
            float ps = 0.f;
#pragma unroll
            for (int r_ = 0; r_ < 2; r_++)
#pragma unroll
                for (int reg = 0; reg < 4; reg++) {
                    int f = (2 * wv + r_) * 16 + quad * 4 + reg;
                    ps += acc[r_][c][reg] * bf2f(Rt[g][f]);
                }
            ps += __shfl_xor(ps, 16); ps += __shfl_xor(ps, 32);
            if (quad == 0) atomicAdd(&vacc[g], ps);
        }
    }
    __syncthreads();
    if (tid < 128) {
        int g = tid;
        float w = 0.f;
        for (int f = 0; f < 128; f++) w += sxv[f] * bf2f(Rt[g][f]);
        float wL = w * (1.f / LL);
        float v2 = vacc[g] * (1.f / LL) - wL * wL;
        float a2 = gamma[g] * rsqrtf(v2 + EPSF);
        a2v[g] = a2;
        ws[OFF_DV + b * FDIM + g] = beta[g] - wL * a2;
    }
    __syncthreads();
    // ---- Ct[g][f] = Rt[g][f] * a2[g]  (bf16, row-major = C^T)
    unsigned short* Ct = (unsigned short*)(ws + OFF_CT) + ((size_t)b << 14);
    {
        int g = tid >> 1, h = tid & 1;
        float a2 = a2v[g];
#pragma unroll
        for (int i = 0; i < 16; i++) {
            int f = h * 64 + i * 4;
            ushort4 r4 = *(ushort4*)&Rt[g][f];
            ushort4 o;
            o.x = bfr(bf2f(r4.x) * a2); o.y = bfr(bf2f(r4.y) * a2);
            o.z = bfr(bf2f(r4.z) * a2); o.w = bfr(bf2f(r4.w) * a2);
            *(ushort4*)&Ct[(g << 7) + f] = o;
        }
    }
}

// ---------------------------------------------------------------- K4: out = X @ C + d
// grid (32 rowchunks, 32 batch), 256 thr; 128x128 tile; XOR-swizzled LDS (64 KB exactly)
__global__ __launch_bounds__(256) void k4_out(const float* __restrict__ x,
                                              const float* __restrict__ ws,
                                              float* __restrict__ out) {
    __shared__ __align__(16) unsigned short Xs[128][128];
    __shared__ __align__(16) unsigned short Cs[128][128];
    const int b = blockIdx.y, r0 = blockIdx.x * 128;
    const int tid = threadIdx.x;
    const int wv = tid >> 6, l15 = tid & 15, quad = (tid >> 4) & 3;
    const float* Xg = x + ((size_t)b * LL + r0) * FDIM;
    const unsigned short* Ct = (const unsigned short*)(ws + OFF_CT) + ((size_t)b << 14);

#pragma unroll
    for (int i = 0; i < 8; i++) {
        int gid = tid + i * 256;            // 0..2047
        int row = gid >> 4, grp = gid & 15;
        const float* src = &Xg[(size_t)row * FDIM + grp * 8];
        float4 v0 = *(const float4*)src, v1 = *(const float4*)(src + 4);
        ushort4 h0, h1;
        h0.x = bfr(v0.x); h0.y = bfr(v0.y); h0.z = bfr(v0.z); h0.w = bfr(v0.w);
        h1.x = bfr(v1.x); h1.y = bfr(v1.y); h1.z = bfr(v1.z); h1.w = bfr(v1.w);
        unsigned short* dst = &Xs[row][(grp ^ (row & 7)) * 8];
        *(ushort4*)dst = h0; *(ushort4*)(dst + 4) = h1;
    }
#pragma unroll
    for (int i = 0; i < 8; i++) {
        int gid = tid + i * 256;
        int row = gid >> 4, grp = gid & 15;
        const unsigned short* src = &Ct[(row << 7) + grp * 8];
        ushort4 c0 = *(const ushort4*)src, c1 = *(const ushort4*)(src + 4);
        unsigned short* dst = &Cs[row][(grp ^ (row & 7)) * 8];
        *(ushort4*)dst = c0; *(ushort4*)(dst + 4) = c1;
    }
    __syncthreads();

    f32x4 acc[2][8];
#pragma unroll
    for (int r_ = 0; r_ < 2; r_++)
#pragma unroll
        for (int c = 0; c < 8; c++) acc[r_][c] = (f32x4){0.f, 0.f, 0.f, 0.f};
#pragma unroll
    for (int k0 = 0; k0 < 128; k0 += 32) {
        const int kq = (k0 >> 3) + quad;
        bf16x8 af[2];
#pragma unroll
        for (int r_ = 0; r_ < 2; r_++) {
            int row = (2 * wv + r_) * 16 + l15;
            af[r_] = *(const bf16x8*)&Xs[row][(kq ^ (row & 7)) * 8];
        }
#pragma unroll
        for (int c = 0; c < 8; c++) {
            int crow = c * 16 + l15;
            bf16x8 bb = *(const bf16x8*)&Cs[crow][(kq ^ (crow & 7)) * 8];
#pragma unroll
            for (int r_ = 0; r_ < 2; r_++)
                acc[r_][c] = __builtin_amdgcn_mfma_f32_16x16x32_bf16(
                    af[r_], bb, acc[r_][c], 0, 0, 0);
        }
    }
    float dreg[8];
#pragma unroll
    for (int c = 0; c < 8; c++) dreg[c] = ws[OFF_DV + b * FDIM + c * 16 + l15];
    float* Ob = out + ((size_t)b * LL + r0) * FDIM;
#pragma unroll
    for (int r_ = 0; r_ < 2; r_++)
#pragma unroll
        for (int c = 0; c < 8; c++)
#pragma unroll
            for (int reg = 0; reg < 4; reg++) {
                int row = (2 * wv + r_) * 16 + quad * 4 + reg;
                Ob[(size_t)row * FDIM + c * 16 + l15] = acc[r_][c][reg] + dreg[c];
            }
}

extern "C" void kernel_launch(void* const* d_in, const int* in_sizes, int n_in,
                              void* d_out, int out_size, void* d_ws, size_t ws_size,
                              hipStream_t stream) {
    const float* x     = (const float*)d_in[0];
    const float* q_w   = (const float*)d_in[1];
    const float* q_b   = (const float*)d_in[2];
    const float* k_w   = (const float*)d_in[3];
    const float* k_b   = (const float*)d_in[4];
    const float* ff_w  = (const float*)d_in[5];
    // ff_b (d_in[6]) cancels exactly under the final instance norm
    const float* gamma = (const float*)d_in[7];
    const float* beta  = (const float*)d_in[8];
    float* out = (float*)d_out;
    float* ws  = (float*)d_ws;

    hipMemsetAsync((char*)d_ws + (size_t)OFF_SX * 4, 0, (size_t)12288 * 4, stream);

    coeff_kernel<<<16, 256, 0, stream>>>(q_w, q_b, k_w, k_b, ws);
    k1_gram<<<dim3(8, 32), 256, 0, stream>>>(x, ws);
    kred<<<128, 256, 0, stream>>>(ws);
    k3_chain<<<32, 256, 0, stream>>>(ws, ff_w, gamma, beta);
    k4_out<<<dim3(32, 32), 256, 0, stream>>>(x, ws, out);
}